// Round 30
// baseline (894.458 us; speedup 1.0000x reference)
//
#include <hip/hip_runtime.h>
#include <math.h>

#define B_    64
#define S_    1024
#define DK_   128
#define DV_   128
#define T_    16
#define NC_   (S_ / T_)
#define KP_   (DK_ + 4)
#define LR_   0.1f
#define LRP1_ 1.1f
#define THR_  0.1f
#define ITEMP_ 10.0f
#define EPS_  1e-6f

template<int CTRL>
__device__ __forceinline__ float dpp_add(float x) {
  int t = __builtin_amdgcn_update_dpp(0, __float_as_int(x), CTRL, 0xf, 0xf, true);
  return x + __int_as_float(t);
}
__device__ __forceinline__ float wave_sum64(float x) {
  x = dpp_add<0x111>(x); x = dpp_add<0x112>(x); x = dpp_add<0x114>(x);
  x = dpp_add<0x118>(x); x = dpp_add<0x142>(x); x = dpp_add<0x143>(x);
  return __int_as_float(__builtin_amdgcn_readlane(__float_as_int(x), 63));
}
__device__ __forceinline__ float row16_sum(float x) {
  x = dpp_add<0x111>(x); x = dpp_add<0x112>(x);
  x = dpp_add<0x114>(x); x = dpp_add<0x118>(x);
  return x;
}
__device__ __forceinline__ float rdlane(float v, int l) {
  return __int_as_float(__builtin_amdgcn_readlane(__float_as_int(v), l));
}
__device__ __forceinline__ float dot4(float4 a, float4 b) {
  return fmaf(a.x, b.x, fmaf(a.y, b.y, fmaf(a.z, b.z, a.w * b.w)));
}
__device__ __forceinline__ void gll16(const float* g, float* l) {
  __builtin_amdgcn_global_load_lds(
      (const __attribute__((address_space(1))) unsigned int*)g,
      (__attribute__((address_space(3))) unsigned int*)l, 16, 0, 0);
}

__global__ __launch_bounds__(576, 1)
void sgm_kernel(const float* __restrict__ mem_in,
                const float* __restrict__ key,
                const float* __restrict__ value,
                float* __restrict__ out) {
  const int b = blockIdx.x, tid = threadIdx.x;
  const int wv = tid >> 6;            // 0..8
  const bool mW = (wv < 8);
  const int g = tid >> 4, h = tid & 15, lane = tid & 63;

  __shared__ __align__(16) float kS[5][T_][KP_];
  __shared__ __align__(16) float vS[4][T_][KP_];
  __shared__ __align__(16) float rawR[2][T_][DK_];
  __shared__ __align__(16) float cuL[2][T_][DK_];
  __shared__ __align__(16) float XG[2][T_][T_];    // XG[p][j][t] = k_j^{c-1}.k_t^{c}
  __shared__ __align__(16) float GT[2][T_][T_];
  __shared__ __align__(16) float gateL[S_];

  float4 mA[4], mB[4];
  if (mW) {
    const float4* Mp = reinterpret_cast<const float4*>(mem_in + (size_t)b * DV_ * DK_);
    #pragma unroll
    for (int rr = 0; rr < 4; ++rr) {
      mA[rr] = Mp[(4*g + rr) * 32 + h];
      mB[rr] = Mp[(4*g + rr) * 32 + 16 + h];
    }
  }
  const float* kb = key   + (size_t)b * S_ * DK_;
  const float* vb = value + (size_t)b * S_ * DV_;

  // Gram decode: tid in [64,336) -> 136 pairs x 2 lanes (j<=t incl diag)
  const int pPair = (tid - 64) >> 1;
  int tP = 0, jP = 0;
  if (tid >= 64 && tid < 336) {
    int t = 0, pp = pPair;
    while (pp > t) { pp -= (t + 1); ++t; }
    tP = t; jP = pp;
  }
  // XG workers: wave 0 (xId 0..63) + waves 5-7 (xId 64..255); 1 lane/pair
  const bool xW = (tid < 64) || (tid >= 320 && tid < 512);
  const int xId = (tid < 64) ? tid : (64 + tid - 320);
  const int xj = xId >> 4, xt = xId & 15;

  auto stage = [&](int cc) {
    if (wv == 0 && lane < 32) {
      #pragma unroll
      for (int t = 0; t < T_; ++t)
        gll16(kb + (size_t)(cc*T_ + t)*DK_ + lane*4, &kS[cc % 5][t][0]);
    }
    if (wv == 1 && lane < 32) {
      #pragma unroll
      for (int t = 0; t < T_; ++t)
        gll16(vb + (size_t)(cc*T_ + t)*DV_ + lane*4, &vS[cc & 3][t][0]);
    }
  };

  auto applyUpdate = [&](int c2) {   // M -= sum_j cu_j (x) k_j (all from LDS)
    const int sl = c2 % 5;
    #pragma unroll
    for (int j = 0; j < T_; ++j) {
      const float4* kj = reinterpret_cast<const float4*>(&kS[sl][j][0]);
      const float4 kx = kj[h], ky = kj[16 + h];
      const float4 cu = *reinterpret_cast<const float4*>(&cuL[c2 & 1][j][4 * g]);
      const float cc4[4] = {cu.x, cu.y, cu.z, cu.w};
      #pragma unroll
      for (int rr = 0; rr < 4; ++rr) {
        mA[rr].x = fmaf(-cc4[rr], kx.x, mA[rr].x);
        mA[rr].y = fmaf(-cc4[rr], kx.y, mA[rr].y);
        mA[rr].z = fmaf(-cc4[rr], kx.z, mA[rr].z);
        mA[rr].w = fmaf(-cc4[rr], kx.w, mA[rr].w);
        mB[rr].x = fmaf(-cc4[rr], ky.x, mB[rr].x);
        mB[rr].y = fmaf(-cc4[rr], ky.y, mB[rr].y);
        mB[rr].z = fmaf(-cc4[rr], ky.z, mB[rr].z);
        mB[rr].w = fmaf(-cc4[rr], ky.w, mB[rr].w);
      }
    }
  };

  // ---- prologue ----
  stage(0); stage(1);
  if (wv < 2) asm volatile("s_waitcnt vmcnt(0)" ::: "memory");
  __syncthreads();

  for (int c = 0; c <= NC_; ++c) {
    const int cb = c & 1;

    if (mW) {
      if (c < NC_) {
        if (c + 2 < NC_) stage(c + 2);
        if (c >= 2) applyUpdate(c - 2);          // M -> M_{c-2}

        const int sl = c % 5;
        // matvec rawRaw_t = M_{c-2} . k_t^{(c)}
        #pragma unroll
        for (int t = 0; t < T_; ++t) {
          const float4* kt = reinterpret_cast<const float4*>(&kS[sl][t][0]);
          const float4 kx = kt[h], ky = kt[16 + h];
          float a0 = dot4(mA[0], kx) + dot4(mB[0], ky);
          float a1 = dot4(mA[1], kx) + dot4(mB[1], ky);
          float a2 = dot4(mA[2], kx) + dot4(mB[2], ky);
          float a3 = dot4(mA[3], kx) + dot4(mB[3], ky);
          a0 = row16_sum(a0); a1 = row16_sum(a1);
          a2 = row16_sum(a2); a3 = row16_sum(a3);
          if (h == 15)
            *reinterpret_cast<float4*>(&rawR[cb][t][4 * g]) = make_float4(a0, a1, a2, a3);
        }

        // cross-Gram X(c-1 -> c): un-rotated reads (broadcast + pad-spread)
        if (c >= 1 && xW) {
          const float4* a4 = reinterpret_cast<const float4*>(&kS[(c - 1) % 5][xj][0]);
          const float4* b4 = reinterpret_cast<const float4*>(&kS[sl][xt][0]);
          float acc = 0.f;
          #pragma unroll
          for (int i = 0; i < 32; ++i) acc += dot4(a4[i], b4[i]);
          XG[cb][xj][xt] = acc;
        }

        // Gram(c) incl diag
        if (tid >= 64 && tid < 336) {
          const int h2 = tid & 1;
          const float4* kj4 = reinterpret_cast<const float4*>(&kS[sl][jP][h2 * 64]);
          const float4* kt4 = reinterpret_cast<const float4*>(&kS[sl][tP][h2 * 64]);
          float acc = 0.f;
          #pragma unroll
          for (int i = 0; i < 16; ++i) acc += dot4(kj4[i], kt4[i]);
          int sw = __builtin_amdgcn_update_dpp(0, __float_as_int(acc), 0xB1, 0xf, 0xf, true);
          const float tot = acc + __int_as_float(sw);
          if (h2 == 0) GT[cb][tP][jP] = tot;
        }
      } else {
        applyUpdate(NC_ - 2);                    // final lag catch-up (part 1)
      }
    } else if (c >= 1) {
      // ---- wave 8: serial(sc = c-1) ----
      const int sc = c - 1, sb = sc & 1;
      const int sl16 = lane & 15;

      if (sc >= 1) {   // correction pass: rawR[sb] -= cu^{(sc-1)} . XG  (LDS RMW)
        const int pb2 = (sc - 1) & 1;
        #pragma unroll
        for (int t = 0; t < T_; ++t) {
          float acc0 = 0.f, acc1 = 0.f;
          #pragma unroll
          for (int j = 0; j < T_; ++j) {
            const float2 cu2 = *reinterpret_cast<const float2*>(&cuL[pb2][j][2 * lane]);
            const float xjt = XG[sb][j][t];      // wave-uniform broadcast
            acc0 = fmaf(cu2.x, xjt, acc0);
            acc1 = fmaf(cu2.y, xjt, acc1);
          }
          float2* rp = reinterpret_cast<float2*>(&rawR[sb][t][2 * lane]);
          const float2 rr = *rp;
          *rp = make_float2(rr.x - acc0, rr.y - acc1);
        }
      }

      float Gr[T_];
      #pragma unroll
      for (int t = 0; t < T_; ++t) Gr[t] = GT[sb][t][sl16];
      const float rinv = 1.0f / (sqrtf(GT[sb][sl16][sl16]) + EPS_);

      float cu0[T_], cu1[T_];
      #pragma unroll
      for (int t = 0; t < T_; ++t) {
        const float rin_t = rdlane(rinv, t);
        float y0 = 0.f, y1 = 0.f;
        #pragma unroll
        for (int j = 0; j < T_; ++j) if (j < t) {
          const float gjt = rdlane(Gr[t], j);
          y0 = fmaf(gjt, cu0[j], y0);
          y1 = fmaf(gjt, cu1[j], y1);
        }
        const float2 rv  = *reinterpret_cast<const float2*>(&rawR[sb][t][2 * lane]);
        const float2 vvt = *reinterpret_cast<const float2*>(&vS[sc & 3][t][2 * lane]);
        const float pred0 = rin_t * (rv.x - y0);
        const float pred1 = rin_t * (rv.y - y1);
        const float s0 = pred0 - vvt.x, s1 = pred1 - vvt.y;
        const float s2 = wave_sum64(fmaf(s0, s0, s1 * s1));
        const float gg = 1.0f / (1.0f + __expf((THR_ - sqrtf(s2)) * ITEMP_));
        if (lane == 0) gateL[sc * T_ + t] = gg;
        const float ct = gg * rin_t;
        const float u0 = fmaf(LRP1_, pred0, -(LR_ * vvt.x));
        const float u1 = fmaf(LRP1_, pred1, -(LR_ * vvt.y));
        cu0[t] = ct * u0; cu1[t] = ct * u1;
        *reinterpret_cast<float2*>(&cuL[sb][t][2 * lane]) = make_float2(cu0[t], cu1[t]);
      }
    }

    if (wv < 2) {
      if (c + 2 < NC_) asm volatile("s_waitcnt vmcnt(16)" ::: "memory");
      else             asm volatile("s_waitcnt vmcnt(0)"  ::: "memory");
    }
    asm volatile("s_waitcnt lgkmcnt(0)" ::: "memory");
    __builtin_amdgcn_s_barrier();   // ONE barrier per chunk
    asm volatile("" ::: "memory");
  }

  if (mW) applyUpdate(NC_ - 1);     // final lag catch-up (part 2)
  __syncthreads();

  // ---- outputs ----
  if (mW) {
    float4* Op = reinterpret_cast<float4*>(out + (size_t)b * DV_ * DK_);
    #pragma unroll
    for (int rr = 0; rr < 4; ++rr) {
      Op[(4*g + rr) * 32 + h] = mA[rr];
      Op[(4*g + rr) * 32 + 16 + h] = mB[rr];
    }
  }
  if (tid < 512) {
    float2* Gp = reinterpret_cast<float2*>(out + (size_t)B_ * DV_ * DK_ + (size_t)b * S_);
    Gp[tid] = reinterpret_cast<const float2*>(gateL)[tid];
  }
}

extern "C" void kernel_launch(void* const* d_in, const int* in_sizes, int n_in,
                              void* d_out, int out_size, void* d_ws, size_t ws_size,
                              hipStream_t stream) {
  const float* mem = (const float*)d_in[0];
  const float* key = (const float*)d_in[1];
  const float* val = (const float*)d_in[2];
  float* out = (float*)d_out;
  sgm_kernel<<<B_, 576, 0, stream>>>(mem, key, val, out);
}

// Round 31
// 541.490 us; speedup vs baseline: 1.6518x; 1.6518x over previous
//
#include <hip/hip_runtime.h>
#include <math.h>

#define B_    64
#define S_    1024
#define DK_   128
#define DV_   128
#define T_    16
#define NC_   (S_ / T_)
#define KP_   (DK_ + 4)    // padded LDS row stride
#define LR_   0.1f
#define LRP1_ 1.1f
#define THR_  0.1f
#define ITEMP_ 10.0f
#define EPS_  1e-6f

template<int CTRL>
__device__ __forceinline__ float dpp_add(float x) {
  int t = __builtin_amdgcn_update_dpp(0, __float_as_int(x), CTRL, 0xf, 0xf, true);
  return x + __int_as_float(t);
}
__device__ __forceinline__ float wave_sum64(float x) {
  x = dpp_add<0x111>(x); x = dpp_add<0x112>(x); x = dpp_add<0x114>(x);
  x = dpp_add<0x118>(x); x = dpp_add<0x142>(x); x = dpp_add<0x143>(x);
  return __int_as_float(__builtin_amdgcn_readlane(__float_as_int(x), 63));
}
__device__ __forceinline__ float row16_sum(float x) {  // valid in lane 15 of each 16-group
  x = dpp_add<0x111>(x); x = dpp_add<0x112>(x);
  x = dpp_add<0x114>(x); x = dpp_add<0x118>(x);
  return x;
}
__device__ __forceinline__ float rdlane(float v, int l) {
  return __int_as_float(__builtin_amdgcn_readlane(__float_as_int(v), l));
}
__device__ __forceinline__ float dot4(float4 a, float4 b) {
  return fmaf(a.x, b.x, fmaf(a.y, b.y, fmaf(a.z, b.z, a.w * b.w)));
}
__device__ __forceinline__ void gll16(const float* g, float* l) {
  __builtin_amdgcn_global_load_lds(
      (const __attribute__((address_space(1))) unsigned int*)g,
      (__attribute__((address_space(3))) unsigned int*)l, 16, 0, 0);
}

__global__ __launch_bounds__(512, 1)
void sgm_kernel(const float* __restrict__ mem_in,
                const float* __restrict__ key,
                const float* __restrict__ value,
                float* __restrict__ out) {
  const int b = blockIdx.x, tid = threadIdx.x;
  const int g = tid >> 4, h = tid & 15, lane = tid & 63, wv = tid >> 6;

  __shared__ __align__(16) float kS[4][T_][KP_];   // ring-4: stage slot != any reader slot
  __shared__ __align__(16) float vS[3][T_][KP_];   // ring-3: stage slot != serial slots
  __shared__ __align__(16) float rawL[T_][DK_];
  __shared__ __align__(16) float cuL[T_][DK_];
  __shared__ __align__(16) float GT[2][T_][T_];    // GT[p][t][j] = k_j.k_t (j<=t)
  __shared__ __align__(16) float gateL[S_];

  float4 mA[4], mB[4];
  {
    const float4* Mp = reinterpret_cast<const float4*>(mem_in + (size_t)b * DV_ * DK_);
    #pragma unroll
    for (int rr = 0; rr < 4; ++rr) {
      mA[rr] = Mp[(4*g + rr) * 32 + h];
      mB[rr] = Mp[(4*g + rr) * 32 + 16 + h];
    }
  }
  const float* kb = key   + (size_t)b * S_ * DK_;
  const float* vb = value + (size_t)b * S_ * DV_;

  // ---- hoisted Gram pair decode: p = t(t+1)/2 + j, j<=t ----
  const int pPair = (tid - 64) >> 1;
  int tP = 0, jP = 0;
  {
    int t = 0, pp = pPair;
    if (wv > 0 && pPair >= 0 && pPair < 136) {
      while (pp > t) { pp -= (t + 1); ++t; }
      tP = t; jP = pp;
    }
  }

  auto stage = [&](int cc) {   // k -> ring slot cc&3 ; v -> ring slot cc%3
    if (wv == 0 && lane < 32) {
      #pragma unroll
      for (int t = 0; t < T_; ++t)
        gll16(kb + (size_t)(cc*T_ + t)*DK_ + lane*4, &kS[cc & 3][t][0]);
    }
    if (wv == 1 && lane < 32) {
      #pragma unroll
      for (int t = 0; t < T_; ++t)
        gll16(vb + (size_t)(cc*T_ + t)*DV_ + lane*4, &vS[cc % 3][t][0]);
    }
  };

  float4 kxR[16];   // current chunk's k first-half float4 (col idx h), saved by matvec

  // M -= sum_j cu_j (x) k_j ; kx from regs (prev matvec), ky+cu from LDS slot sl
  auto applyUpdate = [&](int sl) {
    #pragma unroll
    for (int j = 0; j < T_; ++j) {
      const float4* kj = reinterpret_cast<const float4*>(&kS[sl][j][0]);
      const float4 ky = kj[16 + h];
      const float4 cu = *reinterpret_cast<const float4*>(&cuL[j][4 * g]);
      const float cc4[4] = {cu.x, cu.y, cu.z, cu.w};
      #pragma unroll
      for (int rr = 0; rr < 4; ++rr) {
        mA[rr].x = fmaf(-cc4[rr], kxR[j].x, mA[rr].x);
        mA[rr].y = fmaf(-cc4[rr], kxR[j].y, mA[rr].y);
        mA[rr].z = fmaf(-cc4[rr], kxR[j].z, mA[rr].z);
        mA[rr].w = fmaf(-cc4[rr], kxR[j].w, mA[rr].w);
        mB[rr].x = fmaf(-cc4[rr], ky.x, mB[rr].x);
        mB[rr].y = fmaf(-cc4[rr], ky.y, mB[rr].y);
        mB[rr].z = fmaf(-cc4[rr], ky.z, mB[rr].z);
        mB[rr].w = fmaf(-cc4[rr], ky.w, mB[rr].w);
      }
    }
  };

  // waves 1-7: 136 pairs (incl diag), 2-lane teams, chunk cc
  auto gramPhase = [&](int cc) {
    const int sl = cc & 3, pb = cc & 1;
    const int h2 = tid & 1;
    if (wv > 0 && pPair < 136) {
      const float4* kj4 = reinterpret_cast<const float4*>(&kS[sl][jP][h2*64]);
      const float4* kt4 = reinterpret_cast<const float4*>(&kS[sl][tP][h2*64]);
      float acc = 0.f;
      #pragma unroll
      for (int i = 0; i < 16; ++i) {
        const int ii = (i + pPair) & 15;           // bank-quad decorrelation
        acc += dot4(kj4[ii], kt4[ii]);
      }
      int sw = __builtin_amdgcn_update_dpp(0, __float_as_int(acc), 0xB1, 0xf, 0xf, true);
      const float tot = acc + __int_as_float(sw);
      if (h2 == 0) GT[pb][tP][jP] = tot;
    }
  };

  // ---- prologue: stage chunks 0,1; Gram(0) ----
  stage(0); stage(1);
  if (wv < 2) asm volatile("s_waitcnt vmcnt(0)" ::: "memory");
  __syncthreads();
  gramPhase(0);
  asm volatile("s_waitcnt lgkmcnt(0)" ::: "memory");
  __builtin_amdgcn_s_barrier();          // GT[0] visible
  asm volatile("" ::: "memory");

  for (int c = 0; c < NC_; ++c) {
    const int cb = c & 1;
    const bool staged = (c + 2 < NC_);

    // stage chunk c+2: kS slot (c+2)&3 and vS slot (c+2)%3 are reader-free this iter
    if (staged) stage(c + 2);

    // ---- apply previous chunk's update, then matvec: one fused VALU block ----
    if (c > 0) applyUpdate((c - 1) & 3);

    #pragma unroll
    for (int t = 0; t < T_; ++t) {
      const float4* kt = reinterpret_cast<const float4*>(&kS[c & 3][t][0]);
      const float4 kx = kt[h];
      const float4 ky = kt[16 + h];
      kxR[t] = kx;
      float a0 = dot4(mA[0], kx) + dot4(mB[0], ky);
      float a1 = dot4(mA[1], kx) + dot4(mB[1], ky);
      float a2 = dot4(mA[2], kx) + dot4(mB[2], ky);
      float a3 = dot4(mA[3], kx) + dot4(mB[3], ky);
      a0 = row16_sum(a0); a1 = row16_sum(a1);
      a2 = row16_sum(a2); a3 = row16_sum(a3);
      if (h == 15)
        *reinterpret_cast<float4*>(&rawL[t][4 * g]) = make_float4(a0, a1, a2, a3);
    }

    // stagers: chunk c+1's DMA must be resident; keep this iter's 16 in flight
    if (wv < 2) {
      if (staged) asm volatile("s_waitcnt vmcnt(16)" ::: "memory");
      else        asm volatile("s_waitcnt vmcnt(0)"  ::: "memory");  // tail drain
    }
    asm volatile("s_waitcnt lgkmcnt(0)" ::: "memory");
    __builtin_amdgcn_s_barrier();        // bar A: rawL + kS[(c+1)&3]/vS[(c+1)%3] ready
    asm volatile("" ::: "memory");

    if (wv == 0) {
      // ---- serial phase (hidden under waves 1-7's Gram(c+1)) ----
      const int sj = lane & 15;
      const float rinv = 1.0f / (sqrtf(GT[cb][sj][sj]) + EPS_);
      float cu0[T_], cu1[T_];
      #pragma unroll
      for (int t = 0; t < T_; ++t) {
        const float grt = GT[cb][t][sj];
        const float rin_t = rdlane(rinv, t);
        float y0 = 0.f, y1 = 0.f;
        #pragma unroll
        for (int j = 0; j < T_; ++j) if (j < t) {
          const float gjt = rdlane(grt, j);
          y0 = fmaf(gjt, cu0[j], y0);
          y1 = fmaf(gjt, cu1[j], y1);
        }
        const float2 rv  = *reinterpret_cast<const float2*>(&rawL[t][2*lane]);
        const float2 vvt = *reinterpret_cast<const float2*>(&vS[c % 3][t][2*lane]);
        const float pred0 = rin_t * (rv.x - y0);
        const float pred1 = rin_t * (rv.y - y1);
        const float s0 = pred0 - vvt.x, s1 = pred1 - vvt.y;
        const float s2 = wave_sum64(fmaf(s0, s0, s1 * s1));
        const float gg = 1.0f / (1.0f + __expf((THR_ - sqrtf(s2)) * ITEMP_));
        if (lane == 0) gateL[c*T_ + t] = gg;
        const float ct = gg * rin_t;
        const float u0 = fmaf(LRP1_, pred0, -(LR_ * vvt.x));
        const float u1 = fmaf(LRP1_, pred1, -(LR_ * vvt.y));
        cu0[t] = ct * u0; cu1[t] = ct * u1;
        *reinterpret_cast<float2*>(&cuL[t][2*lane]) = make_float2(cu0[t], cu1[t]);
      }
    } else {
      if (c + 1 < NC_) gramPhase(c + 1);  // GT[(c+1)&1], reads kS[(c+1)&3]
    }

    asm volatile("s_waitcnt lgkmcnt(0)" ::: "memory");
    __builtin_amdgcn_s_barrier();        // bar B: cuL + GT[c+1] visible
    asm volatile("" ::: "memory");
  }

  applyUpdate((NC_ - 1) & 3);

  // ---- outputs ----
  {
    float4* Op = reinterpret_cast<float4*>(out + (size_t)b * DV_ * DK_);
    #pragma unroll
    for (int rr = 0; rr < 4; ++rr) {
      Op[(4*g + rr) * 32 + h] = mA[rr];
      Op[(4*g + rr) * 32 + 16 + h] = mB[rr];
    }
    float2* Gp = reinterpret_cast<float2*>(out + (size_t)B_ * DV_ * DK_ + (size_t)b * S_);
    Gp[tid] = reinterpret_cast<const float2*>(gateL)[tid];
  }
}

extern "C" void kernel_launch(void* const* d_in, const int* in_sizes, int n_in,
                              void* d_out, int out_size, void* d_ws, size_t ws_size,
                              hipStream_t stream) {
  const float* mem = (const float*)d_in[0];
  const float* key = (const float*)d_in[1];
  const float* val = (const float*)d_in[2];
  float* out = (float*)d_out;
  sgm_kernel<<<B_, 512, 0, stream>>>(mem, key, val, out);
}